// Round 13
// baseline (58.238 us; speedup 1.0000x reference)
//
#include <hip/hip_runtime.h>
#include <math.h>

#define M_ROWS 1536
#define NC 96
#define KG 16
#define FD 8192
#define NS 8
#define MARGIN 0.3f

#define KSPLIT 32
#define KCH 256            /* k per block */
#define BKS 32             /* k per stage */
#define NST (KCH / BKS)    /* 8 stages */
#define BN 64              /* n cols per block */

typedef short v8s __attribute__((ext_vector_type(8)));   // 8 bf16
typedef float v4f __attribute__((ext_vector_type(4)));

// async global->LDS, 16B per lane (dest = wave-uniform base + lane*16)
__device__ __forceinline__ void gload16(const float* g, float* lds) {
    __builtin_amdgcn_global_load_lds(
        (const __attribute__((address_space(1))) void*)g,
        (__attribute__((address_space(3))) void*)lds, 16, 0, 0);
}

// in-register truncation split of 8 fp32 (k ascending) -> hi/lo bf16 frags
__device__ __forceinline__ void cvt8(float4 f0, float4 f1, v8s* h, v8s* l) {
    float f[8] = {f0.x, f0.y, f0.z, f0.w, f1.x, f1.y, f1.z, f1.w};
    v8s hh, ll;
#pragma unroll
    for (int j = 0; j < 8; ++j) {
        const unsigned int u = __float_as_uint(f[j]);
        hh[j] = (short)(u >> 16);
        const float r = f[j] - __uint_as_float(u & 0xffff0000u);
        ll[j] = (short)(__float_as_uint(r) >> 16);
    }
    *h = hh; *l = ll;
}

// ---------------- K1: centers + squared-norm partials ----------------
__global__ void centers_kernel(const float* __restrict__ feats,
                               float* __restrict__ centers,
                               float* __restrict__ fnp,   // [4][1536]
                               float* __restrict__ cnp) { // [4][96]
    const int c = blockIdx.x;
    const int bd = blockIdx.y;
    const int tid = threadIdx.x;

    float sq[KG];
#pragma unroll
    for (int k = 0; k < KG; ++k) sq[k] = 0.f;
    float cp = 0.f;

#pragma unroll
    for (int it = 0; it < 2; ++it) {
        const int base = bd * 2048 + it * 1024 + tid * 4;
        float4 acc = make_float4(0.f, 0.f, 0.f, 0.f);
#pragma unroll
        for (int k = 0; k < KG; ++k) {
            const float4 v = *(const float4*)&feats[(size_t)(c * KG + k) * FD + base];
            acc.x += v.x; acc.y += v.y; acc.z += v.z; acc.w += v.w;
            sq[k] += v.x * v.x + v.y * v.y + v.z * v.z + v.w * v.w;
        }
        float4 cv = make_float4(acc.x * 0.0625f, acc.y * 0.0625f,
                                acc.z * 0.0625f, acc.w * 0.0625f);
        *(float4*)&centers[(size_t)c * FD + base] = cv;
        cp += cv.x * cv.x + cv.y * cv.y + cv.z * cv.z + cv.w * cv.w;
    }

    const int lane = tid & 63;
    const int w = tid >> 6;
    __shared__ float wred[4][17];
#pragma unroll
    for (int k = 0; k < KG; ++k) {
        float v = sq[k];
#pragma unroll
        for (int off = 32; off > 0; off >>= 1) v += __shfl_down(v, off, 64);
        if (lane == 0) wred[w][k] = v;
    }
    {
        float v = cp;
#pragma unroll
        for (int off = 32; off > 0; off >>= 1) v += __shfl_down(v, off, 64);
        if (lane == 0) wred[w][16] = v;
    }
    __syncthreads();
    if (tid < 17) {
        const float t = wred[0][tid] + wred[1][tid] + wred[2][tid] + wred[3][tid];
        if (tid < 16) fnp[bd * M_ROWS + c * KG + tid] = t;
        else          cnp[bd * NC + c] = t;
    }
}

// ---------------- K2: bf16x3 MFMA partial GEMM, DMA-staged fp32 ----------------
// 768 blocks = 24 nb x 32 ks (bid%8==ks%8 pins k-slice to one XCD), 4 waves,
// wave = 48m x 32n (2x2 tiling). R13: stage RAW fp32 via global_load_lds
// (k-group-major slots, R7-verified) -- no staging regs, no ds_writes, no
// split VALU in the staging path. hi/lo bf16 split happens in registers at
// fragment-read time: 2x ds_read_b128 fp32 per tile-operand (same instr
// count as pre-split bf16) + ~4 VALU/elem. Double-buffer, 1 barrier/stage.
__global__ __launch_bounds__(256) void gemm13_kernel(const float* __restrict__ centers,
                                                     const float* __restrict__ feats,
                                                     float* __restrict__ part) { // [96][32][1536]
    const int bid = blockIdx.x;
    const int ks = bid & 31;
    const int nb = bid >> 5;
    const int tid = threadIdx.x;
    const int j0 = nb * BN;
    const int k0b = ks * KCH;

    __shared__ float alds[2][NST * NC * 4];   // slot = kkg*96 + row, 12 KB/buf
    __shared__ float blds[2][NST * BN * 4];   // slot = kkg*64 + row,  8 KB/buf

    // per-lane DMA source offsets (only k0 varies per stage)
    int aoff[3], albase[3];
#pragma unroll
    for (int i = 0; i < 3; ++i) {
        const int s = tid + i * 256;              // A: 96x32/4 = 768 slots
        const int kkg = s / NC, r = s - kkg * NC;
        aoff[i] = r * FD + kkg * 4;
        albase[i] = (i * 256 + (tid & 192)) * 4;
    }
    int boff[2], blbase[2];
#pragma unroll
    for (int i = 0; i < 2; ++i) {
        const int s = tid + i * 256;              // B: 64x32/4 = 512 slots
        const int kkg = s >> 6, n = s & 63;
        boff[i] = (j0 + n) * FD + kkg * 4;
        blbase[i] = (i * 256 + (tid & 192)) * 4;
    }

    // prologue: stage 0 -> buf 0
#pragma unroll
    for (int i = 0; i < 3; ++i) gload16(centers + aoff[i] + k0b, &alds[0][albase[i]]);
#pragma unroll
    for (int i = 0; i < 2; ++i) gload16(feats + boff[i] + k0b, &blds[0][blbase[i]]);
    __syncthreads();

    v4f acc[3][2];
#pragma unroll
    for (int a = 0; a < 3; ++a)
#pragma unroll
        for (int b = 0; b < 2; ++b) {
            acc[a][b][0] = 0.f; acc[a][b][1] = 0.f;
            acc[a][b][2] = 0.f; acc[a][b][3] = 0.f;
        }

    const int w = tid >> 6, lane = tid & 63;
    const int wm = w >> 1, wn = w & 1;      // wave: m-tiles wm*3..+2, n-tiles wn*2..+1
    const int r15 = lane & 15, kq = lane >> 4;   // frag: row=r15(+tile), k=kq*8+j

    int cur = 0;
    for (int st = 0; st < NST; ++st) {
        // issue next stage's DMA into the other buffer; flies during compute
        if (st < NST - 1) {
            const int k0 = k0b + (st + 1) * BKS;
#pragma unroll
            for (int i = 0; i < 3; ++i) gload16(centers + aoff[i] + k0, &alds[cur ^ 1][albase[i]]);
#pragma unroll
            for (int i = 0; i < 2; ++i) gload16(feats + boff[i] + k0, &blds[cur ^ 1][blbase[i]]);
        }

        // B fragments: 2 tiles, 2 b128 fp32 reads each, split in regs
        v8s Bh[2], Bl[2];
#pragma unroll
        for (int nt = 0; nt < 2; ++nt) {
            const int row = (wn * 2 + nt) * 16 + r15;
            const int base = (kq * 2 * BN + row) * 4;
            const float4 b0 = *(const float4*)&blds[cur][base];
            const float4 b1 = *(const float4*)&blds[cur][base + BN * 4];
            cvt8(b0, b1, &Bh[nt], &Bl[nt]);
        }
        // A fragments: 3 tiles; 3 MFMA per (mt,nt)
#pragma unroll
        for (int mt = 0; mt < 3; ++mt) {
            const int row = wm * 48 + mt * 16 + r15;
            const int base = (kq * 2 * NC + row) * 4;
            const float4 a0 = *(const float4*)&alds[cur][base];
            const float4 a1 = *(const float4*)&alds[cur][base + NC * 4];
            v8s Ah, Al;
            cvt8(a0, a1, &Ah, &Al);
#pragma unroll
            for (int nt = 0; nt < 2; ++nt) {
                acc[mt][nt] = __builtin_amdgcn_mfma_f32_16x16x32_bf16(Ah, Bh[nt], acc[mt][nt], 0, 0, 0);
                acc[mt][nt] = __builtin_amdgcn_mfma_f32_16x16x32_bf16(Ah, Bl[nt], acc[mt][nt], 0, 0, 0);
                acc[mt][nt] = __builtin_amdgcn_mfma_f32_16x16x32_bf16(Al, Bh[nt], acc[mt][nt], 0, 0, 0);
            }
        }
        __syncthreads();   // drains vmcnt -> next buffer ready
        cur ^= 1;
    }

    // epilogue: C/D layout (m89-verified): col = lane&15, row = (lane>>4)*4 + j
    const int col = lane & 15, r0 = (lane >> 4) * 4;
#pragma unroll
    for (int mt = 0; mt < 3; ++mt) {
#pragma unroll
        for (int nt = 0; nt < 2; ++nt) {
            const int n = j0 + (wn * 2 + nt) * 16 + col;
#pragma unroll
            for (int j = 0; j < 4; ++j) {
                const int m = wm * 48 + mt * 16 + r0 + j;
                part[((size_t)m * KSPLIT + ks) * M_ROWS + n] = acc[mt][nt][j];
            }
        }
    }
}

// ---------------- K3: finalize d2 + masked argmax/argmin ----------------
__global__ void select_kernel(const float* __restrict__ part,
                              const float* __restrict__ fnp,
                              const float* __restrict__ cnp,
                              const int* __restrict__ labels,
                              int* __restrict__ pinds,
                              int* __restrict__ ninds) {
    const int c = blockIdx.x;
    const int tid = threadIdx.x;
    const int anchor = labels[c * KG];

    float cn = 0.f;
#pragma unroll
    for (int b = 0; b < 4; ++b) cn += cnp[b * NC + c];

    float bestp = -INFINITY; int bpi = 1 << 30;
    float bestn =  INFINITY; int bni = 1 << 30;

    const float* pc = part + (size_t)c * KSPLIT * M_ROWS;
    for (int j = tid; j < M_ROWS; j += 256) {
        float dot = 0.f;
#pragma unroll
        for (int p = 0; p < KSPLIT; ++p)
            dot += pc[(size_t)p * M_ROWS + j];
        float fn = 0.f;
#pragma unroll
        for (int b = 0; b < 4; ++b) fn += fnp[b * M_ROWS + j];
        const float d2 = cn + fn - 2.f * dot;
        const bool pos = (labels[j] == anchor);
        if (pos) {
            if (d2 > bestp || (d2 == bestp && j < bpi)) { bestp = d2; bpi = j; }
        } else {
            if (d2 < bestn || (d2 == bestn && j < bni)) { bestn = d2; bni = j; }
        }
    }

    __shared__ float sv[256];
    __shared__ int   si[256];
    sv[tid] = bestp; si[tid] = bpi; __syncthreads();
    for (int s = 128; s > 0; s >>= 1) {
        if (tid < s) {
            if (sv[tid + s] > sv[tid] ||
                (sv[tid + s] == sv[tid] && si[tid + s] < si[tid])) {
                sv[tid] = sv[tid + s]; si[tid] = si[tid + s];
            }
        }
        __syncthreads();
    }
    if (tid == 0) pinds[c] = si[0];
    __syncthreads();
    sv[tid] = bestn; si[tid] = bni; __syncthreads();
    for (int s = 128; s > 0; s >>= 1) {
        if (tid < s) {
            if (sv[tid + s] < sv[tid] ||
                (sv[tid + s] == sv[tid] && si[tid + s] < si[tid])) {
                sv[tid] = sv[tid + s]; si[tid] = si[tid + s];
            }
        }
        __syncthreads();
    }
    if (tid == 0) ninds[c] = si[0];
}

// ---------------- K4: local stripe distances + DP ----------------
__global__ void local_kernel(const float* __restrict__ centers,
                             const float* __restrict__ localf,
                             const int* __restrict__ pinds,
                             const int* __restrict__ ninds,
                             float* __restrict__ res) { // [2][96]
    const int c = blockIdx.x;
    const int which = blockIdx.y;
    const int tid = threadIdx.x;
    const int idx = (which == 0) ? pinds[c] : ninds[c];

    __shared__ float xl[NS * 1028];
    __shared__ float yl[NS * 1032];
    __shared__ float sred[256];
    __shared__ float dmat[64];
    __shared__ float xx[8], yy[8], xyv[64];

#pragma unroll
    for (int it = 0; it < 8; ++it) {
        const int q = tid + it * 256;
        const float4 v = *(const float4*)&centers[(size_t)c * FD + q * 4];
        const int i = q >> 8;
        const int d = (q * 4) & 1023;
        *(float4*)&xl[i * 1028 + d] = v;

        const float4 w = *(const float4*)&localf[(size_t)idx * FD + q * 4];
        const int jb = (q * 4) & 7;
        const int dd = q >> 1;
        yl[(jb + 0) * 1032 + dd] = w.x;
        yl[(jb + 1) * 1032 + dd] = w.y;
        yl[(jb + 2) * 1032 + dd] = w.z;
        yl[(jb + 3) * 1032 + dd] = w.w;
    }
    __syncthreads();

    const int p = tid >> 2, c4 = tid & 3;
    const int i = p >> 3, j = p & 7;
    float s = 0.f;
    for (int t = 0; t < 64; ++t) {
        const int d = c4 * 4 + t * 16;
        const float4 xv = *(const float4*)&xl[i * 1028 + d];
        const float4 yv = *(const float4*)&yl[j * 1032 + d];
        s += xv.x * yv.x + xv.y * yv.y + xv.z * yv.z + xv.w * yv.w;
    }
    sred[tid] = s;
    __syncthreads();
    if (tid < 64)
        xyv[tid] = sred[tid * 4] + sred[tid * 4 + 1] + sred[tid * 4 + 2] + sred[tid * 4 + 3];

    float s2 = 0.f;
    if (tid < 64) {
        const int r = tid >> 2;
        const float* base = (r < 8) ? &xl[r * 1028] : &yl[(r - 8) * 1032];
        for (int t = 0; t < 64; ++t) {
            const int d = c4 * 4 + t * 16;
            const float4 v = *(const float4*)&base[d];
            s2 += v.x * v.x + v.y * v.y + v.z * v.z + v.w * v.w;
        }
    }
    __syncthreads();
    sred[tid] = s2;
    __syncthreads();
    if (tid < 16) {
        const float v = sred[tid * 4] + sred[tid * 4 + 1] + sred[tid * 4 + 2] + sred[tid * 4 + 3];
        if (tid < 8) xx[tid] = v; else yy[tid - 8] = v;
    }
    __syncthreads();

    if (tid < 64) {
        const float d2 = xx[i] + yy[j] - 2.f * xyv[tid];
        const float d = sqrtf(fmaxf(d2, 1e-12f));
        dmat[tid] = tanhf(0.5f * d);
    }
    __syncthreads();

    if (tid == 0) {
        float prev[8], cur[8];
        cur[0] = dmat[0];
#pragma unroll
        for (int jj = 1; jj < 8; ++jj) cur[jj] = cur[jj - 1] + dmat[jj];
        for (int ii = 1; ii < 8; ++ii) {
#pragma unroll
            for (int jj = 0; jj < 8; ++jj) prev[jj] = cur[jj];
            cur[0] = prev[0] + dmat[ii * 8];
#pragma unroll
            for (int jj = 1; jj < 8; ++jj)
                cur[jj] = fminf(prev[jj], cur[jj - 1]) + dmat[ii * 8 + jj];
        }
        res[which * NC + c] = cur[7];
    }
}

// ---------------- K5: mean(relu(ap - an + margin)) ----------------
__global__ void loss_kernel(const float* __restrict__ res, float* __restrict__ out) {
    const int tid = threadIdx.x; // 128
    float v = 0.f;
    if (tid < NC) v = fmaxf(res[tid] - res[NC + tid] + MARGIN, 0.f);
#pragma unroll
    for (int off = 32; off > 0; off >>= 1) v += __shfl_down(v, off, 64);
    __shared__ float w2[2];
    const int lane = tid & 63, w = tid >> 6;
    if (lane == 0) w2[w] = v;
    __syncthreads();
    if (tid == 0) out[0] = (w2[0] + w2[1]) * (1.f / NC);
}

extern "C" void kernel_launch(void* const* d_in, const int* in_sizes, int n_in,
                              void* d_out, int out_size, void* d_ws, size_t ws_size,
                              hipStream_t stream) {
    const float* feats  = (const float*)d_in[0];
    const int*   labels = (const int*)d_in[1];
    const float* localf = (const float*)d_in[2];
    float* out = (float*)d_out;

    float* centers = (float*)d_ws;                          // 96*8192
    float* part    = centers + (size_t)NC * FD;             // 96*32*1536
    float* fnp     = part + (size_t)NC * KSPLIT * M_ROWS;   // 4*1536
    float* cnp     = fnp + 4 * M_ROWS;                      // 4*96
    float* res     = cnp + 4 * NC;                          // 2*96
    int*   pinds   = (int*)(res + 2 * NC);                  // 96
    int*   ninds   = pinds + NC;                            // 96

    hipLaunchKernelGGL(centers_kernel, dim3(NC, 4), dim3(256), 0, stream,
                       feats, centers, fnp, cnp);
    hipLaunchKernelGGL(gemm13_kernel, dim3(24 * KSPLIT), dim3(256), 0, stream,
                       centers, feats, part);
    hipLaunchKernelGGL(select_kernel, dim3(NC), dim3(256), 0, stream,
                       part, fnp, cnp, labels, pinds, ninds);
    hipLaunchKernelGGL(local_kernel, dim3(NC, 2), dim3(256), 0, stream,
                       centers, localf, pinds, ninds, res);
    hipLaunchKernelGGL(loss_kernel, dim3(1), dim3(128), 0, stream, res, out);
}